// Round 1
// baseline (4231.742 us; speedup 1.0000x reference)
//
#include <hip/hip_runtime.h>
#include <hip/hip_bf16.h>
#include <cstdint>

// Problem constants (from reference): B=4,T=16 -> BT=64, N=512, D=128,
// K_SCALES=3, L_LAYERS=3, DK=32, POS_D=16, ALFA_H=32
#define BT 64
#define NN 512
#define DM 128
#define DKE 32
#define KS 3
#define LL 3
#define AHD 32
#define PD 16
#define QKSTRIDE 192  // per-row: 3 scales * (Q,K) * 32
#define INV_SQRT_DK 0.17677669529663687f
#define LN_EPS_F 1e-5f

__device__ __forceinline__ float wave_rmax(float v) {
#pragma unroll
  for (int o = 32; o > 0; o >>= 1) v = fmaxf(v, __shfl_xor(v, o, 64));
  return v;
}
__device__ __forceinline__ float wave_rsum(float v) {
#pragma unroll
  for (int o = 32; o > 0; o >>= 1) v += __shfl_xor(v, o, 64);
  return v;
}

// --- K0: spatial masks M[k][i][j] = exp(-D2(i,j) / (2*sigma_k^2)) ---------
__global__ void k_msp(const float* __restrict__ pos, const float* __restrict__ log_sigma,
                      float* __restrict__ M) {
  int j = blockIdx.x * 256 + threadIdx.x;
  int i = blockIdx.y;
  const float* pi = pos + i * PD;  // uniform -> scalar loads
  const float* pj = pos + j * PD;
  float d2 = 0.f;
#pragma unroll
  for (int p = 0; p < PD; ++p) {
    float df = pi[p] - pj[p];
    d2 += df * df;
  }
#pragma unroll
  for (int k = 0; k < KS; ++k) {
    float sg = fmaxf(__expf(log_sigma[k]), 1e-3f);
    float c = -0.5f / (sg * sg);
    M[(size_t)k * NN * NN + (size_t)i * NN + j] = __expf(c * d2);
  }
}

// --- K1: per-bt scale-mix weights alpha[bt][3] ----------------------------
__global__ void k_alpha(const float* __restrict__ h, const float* __restrict__ Wa_w,
                        const float* __restrict__ Wa_b, const float* __restrict__ wa_w,
                        const float* __restrict__ wa_b, int l, float* __restrict__ alpha) {
  int bt = blockIdx.x;
  int tid = threadIdx.x;          // 512 threads
  int d = tid & (DM - 1);
  int sl = tid >> 7;              // 0..3 n-slices
  __shared__ float part[4][DM];
  __shared__ float hm[DM];
  __shared__ float ah[AHD];
  const float* hb = h + (size_t)bt * NN * DM;
  float s = 0.f;
  for (int nn = 0; nn < NN / 4; ++nn) s += hb[(size_t)(sl * (NN / 4) + nn) * DM + d];
  part[sl][d] = s;
  __syncthreads();
  if (sl == 0) hm[d] = (part[0][d] + part[1][d] + part[2][d] + part[3][d]) * (1.f / NN);
  __syncthreads();
  if (tid < AHD) {
    const float* w = Wa_w + ((size_t)l * AHD + tid) * DM;
    float a = Wa_b[l * AHD + tid];
    for (int dd = 0; dd < DM; ++dd) a += hm[dd] * w[dd];
    ah[tid] = fmaxf(a, 0.f);
  }
  __syncthreads();
  if (tid == 0) {
    float lg[KS];
    float m = -1e30f;
    for (int k = 0; k < KS; ++k) {
      float v = wa_b[l * KS + k];
      const float* w = wa_w + ((size_t)l * KS + k) * AHD;
      for (int hh = 0; hh < AHD; ++hh) v += ah[hh] * w[hh];
      lg[k] = v;
      m = fmaxf(m, v);
    }
    float se = 0.f;
    for (int k = 0; k < KS; ++k) {
      lg[k] = __expf(lg[k] - m);
      se += lg[k];
    }
    float inv = 1.f / se;
    for (int k = 0; k < KS; ++k) alpha[bt * KS + k] = lg[k] * inv;
  }
}

// --- K2: Q/K projections for all 3 scales: QK[bt][n][k][{q,k}][32] --------
__global__ void k_qkproj(const float* __restrict__ h, const float* __restrict__ WQ_w,
                         const float* __restrict__ WQ_b, const float* __restrict__ WK_w,
                         const float* __restrict__ WK_b, float* __restrict__ QK) {
  int bt = blockIdx.y;
  int n0 = blockIdx.x * 4;
  int tid = threadIdx.x;  // 192 threads = 3 waves; one output column each
  __shared__ float hl[4 * DM];
  const float* hb = h + ((size_t)bt * NN + n0) * DM;  // 512 contiguous floats
  for (int i = tid; i < 4 * DM; i += 192) hl[i] = hb[i];
  __syncthreads();
  int k = tid >> 6;
  int rem = tid & 63;
  int qk = rem >> 5;
  int e = rem & 31;
  const float* W = (qk ? WK_w : WQ_w) + ((size_t)k * DKE + e) * DM;
  float bias = (qk ? WK_b : WQ_b)[k * DKE + e];
  float acc[4] = {bias, bias, bias, bias};
  const float4* W4 = (const float4*)W;
  const float4* h4 = (const float4*)hl;
#pragma unroll 8
  for (int d4 = 0; d4 < DM / 4; ++d4) {
    float4 w = W4[d4];
#pragma unroll
    for (int r = 0; r < 4; ++r) {
      float4 hv = h4[r * 32 + d4];
      acc[r] += w.x * hv.x + w.y * hv.y + w.z * hv.z + w.w * hv.w;
    }
  }
  float* out = QK + ((size_t)bt * NN + n0) * QKSTRIDE + tid;
#pragma unroll
  for (int r = 0; r < 4; ++r) out[r * QKSTRIDE] = acc[r];
}

// --- K3: fused 3-scale masked attention -> h_agg --------------------------
// 4 rows/block (row per wave). Scales combined into one PV weight vector:
//   w[j] = sum_k alpha_k * softmax_k(row)[j];  h_agg[row] = w @ h
__global__ void __launch_bounds__(256) k_attn(
    const float* __restrict__ h, const float* __restrict__ QK,
    const float* __restrict__ M, const float* __restrict__ alpha,
    float* __restrict__ hagg) {
  int bt = blockIdx.y;
  int n0 = blockIdx.x * 4;
  int tid = threadIdx.x;
  int wv = tid >> 6, lane = tid & 63;
  int n = n0 + wv;
  __shared__ float wl[4][NN];    // combined PV weights per row
  __shared__ float red[8][512];  // PV partials over 8 j-slices
  float al[KS];
#pragma unroll
  for (int k = 0; k < KS; ++k) al[k] = alpha[bt * KS + k];
  float wsum[8] = {0.f, 0.f, 0.f, 0.f, 0.f, 0.f, 0.f, 0.f};
#pragma unroll
  for (int k = 0; k < KS; ++k) {
    const float4* Qp = (const float4*)(QK + ((size_t)bt * NN + n) * QKSTRIDE + k * 64);
    float q[32];
#pragma unroll
    for (int i = 0; i < 8; ++i) {
      float4 t = Qp[i];
      q[4 * i] = t.x; q[4 * i + 1] = t.y; q[4 * i + 2] = t.z; q[4 * i + 3] = t.w;
    }
    float p[8];
    float mloc = -1e30f;
#pragma unroll
    for (int jj = 0; jj < 8; ++jj) {
      int j = jj * 64 + lane;
      const float4* Kp = (const float4*)(QK + ((size_t)bt * NN + j) * QKSTRIDE + k * 64 + DKE);
      float dot = 0.f;
#pragma unroll
      for (int i = 0; i < 8; ++i) {
        float4 t = Kp[i];
        dot += q[4 * i] * t.x + q[4 * i + 1] * t.y + q[4 * i + 2] * t.z + q[4 * i + 3] * t.w;
      }
      float sv = dot * INV_SQRT_DK * M[(size_t)k * NN * NN + (size_t)n * NN + j];
      p[jj] = sv;
      mloc = fmaxf(mloc, sv);
    }
    float m = wave_rmax(mloc);
    float lsum = 0.f;
#pragma unroll
    for (int jj = 0; jj < 8; ++jj) {
      p[jj] = __expf(p[jj] - m);
      lsum += p[jj];
    }
    lsum = wave_rsum(lsum);
    float sc = al[k] / lsum;  // rows of softmax sum to 1 -> deg==1, skip deg
#pragma unroll
    for (int jj = 0; jj < 8; ++jj) wsum[jj] += p[jj] * sc;
  }
#pragma unroll
  for (int jj = 0; jj < 8; ++jj) wl[wv][jj * 64 + lane] = wsum[jj];
  __syncthreads();
  // PV: 256 threads = 32 d-quads x 8 j-slices
  int dg = tid & 31, slc = tid >> 5;
  int d0 = dg * 4;
  float4 acc[4];
#pragma unroll
  for (int r = 0; r < 4; ++r) acc[r] = make_float4(0.f, 0.f, 0.f, 0.f);
  const float* hb = h + (size_t)bt * NN * DM;
  for (int jo = 0; jo < 64; ++jo) {
    int j = slc * 64 + jo;
    float4 hv = *(const float4*)(hb + (size_t)j * DM + d0);
#pragma unroll
    for (int r = 0; r < 4; ++r) {
      float wr = wl[r][j];
      acc[r].x += wr * hv.x; acc[r].y += wr * hv.y;
      acc[r].z += wr * hv.z; acc[r].w += wr * hv.w;
    }
  }
#pragma unroll
  for (int r = 0; r < 4; ++r) *(float4*)&red[slc][r * DM + d0] = acc[r];
  __syncthreads();
  for (int idx = tid; idx < 4 * DM; idx += 256) {
    float s = 0.f;
#pragma unroll
    for (int s2 = 0; s2 < 8; ++s2) s += red[s2][idx];
    int r = idx >> 7, d = idx & (DM - 1);
    hagg[((size_t)bt * NN + n0 + r) * DM + d] = s;
  }
}

// --- K4: h = LayerNorm(h + relu(h_agg @ gcn_w^T + gcn_b)) (in place) ------
__global__ void k_gcnln(float* __restrict__ h, const float* __restrict__ hagg,
                        const float* __restrict__ gcn_w, const float* __restrict__ gcn_b,
                        const float* __restrict__ ln_g, const float* __restrict__ ln_b,
                        int l) {
  int bt = blockIdx.y, n0 = blockIdx.x * 4, tid = threadIdx.x;  // 128 threads
  __shared__ float gl[4 * DM];
  __shared__ float red[2][4][2];
  const float* gb = hagg + ((size_t)bt * NN + n0) * DM;
  for (int i = tid; i < 4 * DM; i += 128) gl[i] = gb[i];
  __syncthreads();
  int d = tid;
  const float* W = gcn_w + ((size_t)l * DM + d) * DM;
  float b0 = gcn_b[l * DM + d];
  float acc[4] = {b0, b0, b0, b0};
  const float4* W4 = (const float4*)W;
  const float4* g4 = (const float4*)gl;
#pragma unroll 8
  for (int d4 = 0; d4 < DM / 4; ++d4) {
    float4 w = W4[d4];
#pragma unroll
    for (int r = 0; r < 4; ++r) {
      float4 hv = g4[r * 32 + d4];
      acc[r] += w.x * hv.x + w.y * hv.y + w.z * hv.z + w.w * hv.w;
    }
  }
  float* hb = h + ((size_t)bt * NN + n0) * DM;
  float y[4];
#pragma unroll
  for (int r = 0; r < 4; ++r) y[r] = hb[(size_t)r * DM + d] + fmaxf(acc[r], 0.f);
  int wv = tid >> 6, lane = tid & 63;
#pragma unroll
  for (int r = 0; r < 4; ++r) {
    float s1 = wave_rsum(y[r]);
    float s2 = wave_rsum(y[r] * y[r]);
    if (lane == 0) { red[wv][r][0] = s1; red[wv][r][1] = s2; }
  }
  __syncthreads();
  float g = ln_g[l * DM + d], bb = ln_b[l * DM + d];
#pragma unroll
  for (int r = 0; r < 4; ++r) {
    float mu = (red[0][r][0] + red[1][r][0]) * (1.f / DM);
    float ms = (red[0][r][1] + red[1][r][1]) * (1.f / DM);
    float var = ms - mu * mu;
    float inv = rsqrtf(var + LN_EPS_F);
    hb[(size_t)r * DM + d] = (y[r] - mu) * inv * g + bb;
  }
}

extern "C" void kernel_launch(void* const* d_in, const int* in_sizes, int n_in,
                              void* d_out, int out_size, void* d_ws, size_t ws_size,
                              hipStream_t stream) {
  const float* x         = (const float*)d_in[0];
  const float* node_pos  = (const float*)d_in[1];
  const float* log_sigma = (const float*)d_in[2];
  const float* WQ_w      = (const float*)d_in[3];
  const float* WQ_b      = (const float*)d_in[4];
  const float* WK_w      = (const float*)d_in[5];
  const float* WK_b      = (const float*)d_in[6];
  const float* gcn_w     = (const float*)d_in[7];
  const float* gcn_b     = (const float*)d_in[8];
  const float* Wa_w      = (const float*)d_in[9];
  const float* Wa_b      = (const float*)d_in[10];
  const float* wa_w      = (const float*)d_in[11];
  const float* wa_b      = (const float*)d_in[12];
  const float* ln_g      = (const float*)d_in[13];
  const float* ln_b      = (const float*)d_in[14];

  float* h = (float*)d_out;  // h state lives in d_out; final h IS the output
  float* ws = (float*)d_ws;
  // workspace layout (floats): total ~11.3M floats ~45.1 MB
  float* Msp   = ws;                                    // 3*512*512   = 786432
  float* QK    = Msp + (size_t)KS * NN * NN;            // 64*512*192  = 6291456
  float* hagg  = QK + (size_t)BT * NN * QKSTRIDE;       // 64*512*128  = 4194304
  float* alpha = hagg + (size_t)BT * NN * DM;           // 64*3

  hipMemcpyAsync(h, x, (size_t)BT * NN * DM * sizeof(float),
                 hipMemcpyDeviceToDevice, stream);
  k_msp<<<dim3(2, NN), 256, 0, stream>>>(node_pos, log_sigma, Msp);
  for (int l = 0; l < LL; ++l) {
    k_alpha<<<BT, 512, 0, stream>>>(h, Wa_w, Wa_b, wa_w, wa_b, l, alpha);
    k_qkproj<<<dim3(NN / 4, BT), 192, 0, stream>>>(h, WQ_w, WQ_b, WK_w, WK_b, QK);
    k_attn<<<dim3(NN / 4, BT), 256, 0, stream>>>(h, QK, Msp, alpha, hagg);
    k_gcnln<<<dim3(NN / 4, BT), 128, 0, stream>>>(h, hagg, gcn_w, gcn_b, ln_g, ln_b, l);
  }
}

// Round 4
// 1341.968 us; speedup vs baseline: 3.1534x; 3.1534x over previous
//
#include <hip/hip_runtime.h>
#include <hip/hip_bf16.h>
#include <cstdint>

// Problem constants: B=4,T=16 -> BT=64, N=512, D=128, K_SCALES=3, L_LAYERS=3,
// DK=32, POS_D=16, ALFA_H=32
#define BT 64
#define NN 512
#define DM 128
#define DKE 32
#define KS 3
#define LL 3
#define AHD 32
#define PD 16
#define QSTRIDE 96   // per-row Q: 3 scales * 32 (bf16)
#define RB 16        // rows per attn block
#define JT 128       // scores j-tile
#define JT2 64       // PV j-tile
#define INV_SQRT_DK 0.17677669529663687f
#define LN_EPS_F 1e-5f

__device__ __forceinline__ float wave_rmax(float v) {
#pragma unroll
  for (int o = 32; o > 0; o >>= 1) v = fmaxf(v, __shfl_xor(v, o, 64));
  return v;
}
__device__ __forceinline__ float wave_rsum(float v) {
#pragma unroll
  for (int o = 32; o > 0; o >>= 1) v += __shfl_xor(v, o, 64);
  return v;
}
__device__ __forceinline__ ushort f2bf(float f) {
  uint32_t u = __float_as_uint(f);
  u += 0x7fffu + ((u >> 16) & 1u);   // round-to-nearest-even
  return (ushort)(u >> 16);
}
__device__ __forceinline__ float bflo(uint v) { return __uint_as_float(v << 16); }
__device__ __forceinline__ float bfhi(uint v) { return __uint_as_float(v & 0xffff0000u); }

// --- K_init: h(f32, d_out) = x; hb16 = bf16(x) ----------------------------
__global__ void k_init(const float* __restrict__ x, float* __restrict__ h,
                       ushort* __restrict__ hb16) {
  int i = blockIdx.x * 256 + threadIdx.x;  // float4 index, 1048576 total
  float4 v = ((const float4*)x)[i];
  ((float4*)h)[i] = v;
  ushort4 u;
  u.x = f2bf(v.x); u.y = f2bf(v.y); u.z = f2bf(v.z); u.w = f2bf(v.w);
  ((ushort4*)hb16)[i] = u;
}

// --- K0: spatial masks M[k][i][j] = exp(-D2(i,j) / (2*sigma_k^2)) ---------
__global__ void k_msp(const float* __restrict__ pos, const float* __restrict__ log_sigma,
                      float* __restrict__ M) {
  int j = blockIdx.x * 256 + threadIdx.x;
  int i = blockIdx.y;
  const float* pi = pos + i * PD;
  const float* pj = pos + j * PD;
  float d2 = 0.f;
#pragma unroll
  for (int p = 0; p < PD; ++p) {
    float df = pi[p] - pj[p];
    d2 += df * df;
  }
#pragma unroll
  for (int k = 0; k < KS; ++k) {
    float sg = fmaxf(__expf(log_sigma[k]), 1e-3f);
    float c = -0.5f / (sg * sg);
    M[(size_t)k * NN * NN + (size_t)i * NN + j] = __expf(c * d2);
  }
}

// --- K1: per-bt scale-mix weights alpha[bt][3] ----------------------------
__global__ void k_alpha(const float* __restrict__ h, const float* __restrict__ Wa_w,
                        const float* __restrict__ Wa_b, const float* __restrict__ wa_w,
                        const float* __restrict__ wa_b, int l, float* __restrict__ alpha) {
  int bt = blockIdx.x;
  int tid = threadIdx.x;  // 512 threads
  int d = tid & (DM - 1);
  int sl = tid >> 7;
  __shared__ float part[4][DM];
  __shared__ float hm[DM];
  __shared__ float ah[AHD];
  const float* hb = h + (size_t)bt * NN * DM;
  float s = 0.f;
  for (int nn = 0; nn < NN / 4; ++nn) s += hb[(size_t)(sl * (NN / 4) + nn) * DM + d];
  part[sl][d] = s;
  __syncthreads();
  if (sl == 0) hm[d] = (part[0][d] + part[1][d] + part[2][d] + part[3][d]) * (1.f / NN);
  __syncthreads();
  if (tid < AHD) {
    const float* w = Wa_w + ((size_t)l * AHD + tid) * DM;
    float a = Wa_b[l * AHD + tid];
    for (int dd = 0; dd < DM; ++dd) a += hm[dd] * w[dd];
    ah[tid] = fmaxf(a, 0.f);
  }
  __syncthreads();
  if (tid == 0) {
    float lg[KS];
    float m = -1e30f;
    for (int k = 0; k < KS; ++k) {
      float v = wa_b[l * KS + k];
      const float* w = wa_w + ((size_t)l * KS + k) * AHD;
      for (int hh = 0; hh < AHD; ++hh) v += ah[hh] * w[hh];
      lg[k] = v;
      m = fmaxf(m, v);
    }
    float se = 0.f;
    for (int k = 0; k < KS; ++k) {
      lg[k] = __expf(lg[k] - m);
      se += lg[k];
    }
    float inv = 1.f / se;
    for (int k = 0; k < KS; ++k) alpha[bt * KS + k] = lg[k] * inv;
  }
}

// --- K2: Q/K projections; Q bf16 row-major [bt][n][k*32+e], K bf16
//     TRANSPOSED [bt][k][e][j] for coalesced j-access in k_attn -----------
__global__ void k_qkproj(const float* __restrict__ h, const float* __restrict__ WQ_w,
                         const float* __restrict__ WQ_b, const float* __restrict__ WK_w,
                         const float* __restrict__ WK_b, ushort* __restrict__ Qb,
                         ushort* __restrict__ KT) {
  int bt = blockIdx.y;
  int n0 = blockIdx.x * 4;
  int tid = threadIdx.x;  // 192 threads
  __shared__ float hl[4 * DM];
  const float* hbp = h + ((size_t)bt * NN + n0) * DM;
  for (int i = tid; i < 4 * DM; i += 192) hl[i] = hbp[i];
  __syncthreads();
  int k = tid >> 6;
  int rem = tid & 63;
  int qk = rem >> 5;
  int e = rem & 31;
  const float* W = (qk ? WK_w : WQ_w) + ((size_t)k * DKE + e) * DM;
  float bias = (qk ? WK_b : WQ_b)[k * DKE + e];
  float acc[4] = {bias, bias, bias, bias};
  const float4* W4 = (const float4*)W;
  const float4* h4 = (const float4*)hl;
#pragma unroll 8
  for (int d4 = 0; d4 < DM / 4; ++d4) {
    float4 w = W4[d4];
#pragma unroll
    for (int r = 0; r < 4; ++r) {
      float4 hv = h4[r * 32 + d4];
      acc[r] += w.x * hv.x + w.y * hv.y + w.z * hv.z + w.w * hv.w;
    }
  }
  if (qk == 0) {
    ushort* out = Qb + ((size_t)bt * NN + n0) * QSTRIDE + k * DKE + e;
#pragma unroll
    for (int r = 0; r < 4; ++r) out[(size_t)r * QSTRIDE] = f2bf(acc[r]);
  } else {
    ushort4 u;
    u.x = f2bf(acc[0]); u.y = f2bf(acc[1]); u.z = f2bf(acc[2]); u.w = f2bf(acc[3]);
    *(ushort4*)(KT + ((size_t)(bt * KS + k) * DKE + e) * NN + n0) = u;
  }
}

// --- K3: fused 3-scale masked attention -> h_agg --------------------------
// 512 threads, 16 rows/block. K-tiles + h-tiles staged in LDS, shared by
// all 8 waves; each wave owns 2 rows, scores fully in registers.
__global__ void __launch_bounds__(512, 4) k_attn(
    const ushort* __restrict__ Qb, const ushort* __restrict__ KT,
    const ushort* __restrict__ hb, const float* __restrict__ M,
    const float* __restrict__ alpha, float* __restrict__ hagg) {
  int bt = blockIdx.y;
  int n0 = blockIdx.x * RB;
  int tid = threadIdx.x;
  int wv = tid >> 6, lane = tid & 63;

  __shared__ float q_lds[RB * QSTRIDE];      // 6 KB
  __shared__ uint kst[KS * DKE * (JT / 2)];  // 24 KB (reused as h-tile in PV)
  __shared__ float wl[RB * NN];              // 32 KB

  // stage Q (bf16 -> f32)
  {
    const uint* qsrc = (const uint*)(Qb + (size_t)(bt * NN + n0) * QSTRIDE);
    for (int i = tid; i < RB * QSTRIDE / 2; i += 512) {
      uint v = qsrc[i];
      q_lds[2 * i] = bflo(v);
      q_lds[2 * i + 1] = bfhi(v);
    }
  }

  float al[KS];
#pragma unroll
  for (int k = 0; k < KS; ++k) al[k] = alpha[bt * KS + k];

  int r0 = wv * 2, r1 = r0 + 1;
  float s0[KS][8], s1[KS][8];
  const uint2* ktb = (const uint2*)(KT + (size_t)bt * KS * DKE * NN);

#pragma unroll
  for (int t = 0; t < NN / JT; ++t) {
    __syncthreads();  // prev tile reads done (and q_lds writes for t==0)
    // stage KT tile: [96 rows=(k,e)][128 j] bf16 = 3072 uint2 chunks
#pragma unroll
    for (int c = 0; c < 6; ++c) {
      int idx = tid + c * 512;
      int ke = idx >> 5, jc = idx & 31;
      uint2 v = ktb[(size_t)ke * (NN / 4) + t * (JT / 4) + jc];
      *(uint2*)&kst[ke * (JT / 2) + jc * 2] = v;
    }
    __syncthreads();
#pragma unroll
    for (int k = 0; k < KS; ++k) {
      const float* q0p = &q_lds[r0 * QSTRIDE + k * DKE];
      const float* q1p = &q_lds[r1 * QSTRIDE + k * DKE];
      float d00 = 0.f, d01 = 0.f, d10 = 0.f, d11 = 0.f;
#pragma unroll
      for (int e = 0; e < DKE; ++e) {
        uint kv = kst[(k * DKE + e) * (JT / 2) + lane];  // 2 bf16 (j pair)
        float f0 = bflo(kv), f1 = bfhi(kv);
        float q0 = q0p[e], q1 = q1p[e];
        d00 += q0 * f0; d01 += q0 * f1;
        d10 += q1 * f0; d11 += q1 * f1;
      }
      int jb = t * JT + lane * 2;
      float2 m0 = *(const float2*)(M + ((size_t)k * NN + n0 + r0) * NN + jb);
      float2 m1 = *(const float2*)(M + ((size_t)k * NN + n0 + r1) * NN + jb);
      s0[k][2 * t] = d00 * INV_SQRT_DK * m0.x;
      s0[k][2 * t + 1] = d01 * INV_SQRT_DK * m0.y;
      s1[k][2 * t] = d10 * INV_SQRT_DK * m1.x;
      s1[k][2 * t + 1] = d11 * INV_SQRT_DK * m1.y;
    }
  }

  // per-row per-scale softmax (deg==1 exactly), combine scales with alpha
  float w0[8], w1[8];
#pragma unroll
  for (int g = 0; g < 8; ++g) { w0[g] = 0.f; w1[g] = 0.f; }
#pragma unroll
  for (int k = 0; k < KS; ++k) {
    float mx0 = s0[k][0], mx1 = s1[k][0];
#pragma unroll
    for (int g = 1; g < 8; ++g) { mx0 = fmaxf(mx0, s0[k][g]); mx1 = fmaxf(mx1, s1[k][g]); }
    mx0 = wave_rmax(mx0);
    mx1 = wave_rmax(mx1);
    float l0 = 0.f, l1 = 0.f;
#pragma unroll
    for (int g = 0; g < 8; ++g) {
      s0[k][g] = __expf(s0[k][g] - mx0); l0 += s0[k][g];
      s1[k][g] = __expf(s1[k][g] - mx1); l1 += s1[k][g];
    }
    l0 = wave_rsum(l0);
    l1 = wave_rsum(l1);
    float c0 = al[k] / l0, c1 = al[k] / l1;
#pragma unroll
    for (int g = 0; g < 8; ++g) { w0[g] += c0 * s0[k][g]; w1[g] += c1 * s1[k][g]; }
  }
#pragma unroll
  for (int t = 0; t < 4; ++t) {
    *(float2*)&wl[r0 * NN + t * JT + lane * 2] = make_float2(w0[2 * t], w0[2 * t + 1]);
    *(float2*)&wl[r1 * NN + t * JT + lane * 2] = make_float2(w1[2 * t], w1[2 * t + 1]);
  }

  // PV: thread owns (row = tid>>5, d-quad = (tid&31)*4), full j range
  int prow = tid >> 5;
  int d0 = (tid & 31) * 4;
  float a0 = 0.f, a1 = 0.f, a2 = 0.f, a3 = 0.f;
  const uint4* hsrc = (const uint4*)(hb + (size_t)bt * NN * DM);
#pragma unroll
  for (int t2 = 0; t2 < NN / JT2; ++t2) {
    __syncthreads();  // wl written / prev h-tile reads done
    ((uint4*)kst)[tid] = hsrc[t2 * 1024 + tid];
    ((uint4*)kst)[tid + 512] = hsrc[t2 * 1024 + tid + 512];
    __syncthreads();
    const float* wrow = &wl[prow * NN + t2 * JT2];
#pragma unroll 4
    for (int j = 0; j < JT2; j += 2) {
      float2 wp = *(const float2*)&wrow[j];
      uint2 ha = *(const uint2*)&kst[j * (DM / 2) + (d0 >> 1)];
      uint2 hc = *(const uint2*)&kst[(j + 1) * (DM / 2) + (d0 >> 1)];
      a0 += wp.x * bflo(ha.x); a1 += wp.x * bfhi(ha.x);
      a2 += wp.x * bflo(ha.y); a3 += wp.x * bfhi(ha.y);
      a0 += wp.y * bflo(hc.x); a1 += wp.y * bfhi(hc.x);
      a2 += wp.y * bflo(hc.y); a3 += wp.y * bfhi(hc.y);
    }
  }
  *(float4*)&hagg[((size_t)bt * NN + n0 + prow) * DM + d0] = make_float4(a0, a1, a2, a3);
}

// --- K4: h = LayerNorm(h + relu(h_agg @ gcn_w^T + gcn_b)); also hb16 ------
__global__ void k_gcnln(float* __restrict__ h, const float* __restrict__ hagg,
                        const float* __restrict__ gcn_w, const float* __restrict__ gcn_b,
                        const float* __restrict__ ln_g, const float* __restrict__ ln_b,
                        int l, ushort* __restrict__ hb16) {
  int bt = blockIdx.y, n0 = blockIdx.x * 4, tid = threadIdx.x;  // 128 threads
  __shared__ float gl[4 * DM];
  __shared__ float red[2][4][2];
  const float* gb = hagg + ((size_t)bt * NN + n0) * DM;
  for (int i = tid; i < 4 * DM; i += 128) gl[i] = gb[i];
  __syncthreads();
  int d = tid;
  const float* W = gcn_w + ((size_t)l * DM + d) * DM;
  float b0 = gcn_b[l * DM + d];
  float acc[4] = {b0, b0, b0, b0};
  const float4* W4 = (const float4*)W;
  const float4* g4 = (const float4*)gl;
#pragma unroll 8
  for (int d4 = 0; d4 < DM / 4; ++d4) {
    float4 w = W4[d4];
#pragma unroll
    for (int r = 0; r < 4; ++r) {
      float4 hv = g4[r * 32 + d4];
      acc[r] += w.x * hv.x + w.y * hv.y + w.z * hv.z + w.w * hv.w;
    }
  }
  float* hbp = h + ((size_t)bt * NN + n0) * DM;
  float y[4];
#pragma unroll
  for (int r = 0; r < 4; ++r) y[r] = hbp[(size_t)r * DM + d] + fmaxf(acc[r], 0.f);
  int wv = tid >> 6, lane = tid & 63;
#pragma unroll
  for (int r = 0; r < 4; ++r) {
    float s1 = wave_rsum(y[r]);
    float s2 = wave_rsum(y[r] * y[r]);
    if (lane == 0) { red[wv][r][0] = s1; red[wv][r][1] = s2; }
  }
  __syncthreads();
  float g = ln_g[l * DM + d], bb = ln_b[l * DM + d];
#pragma unroll
  for (int r = 0; r < 4; ++r) {
    float mu = (red[0][r][0] + red[1][r][0]) * (1.f / DM);
    float ms = (red[0][r][1] + red[1][r][1]) * (1.f / DM);
    float var = ms - mu * mu;
    float inv = rsqrtf(var + LN_EPS_F);
    float v = (y[r] - mu) * inv * g + bb;
    hbp[(size_t)r * DM + d] = v;
    hb16[((size_t)bt * NN + n0 + r) * DM + d] = f2bf(v);
  }
}

extern "C" void kernel_launch(void* const* d_in, const int* in_sizes, int n_in,
                              void* d_out, int out_size, void* d_ws, size_t ws_size,
                              hipStream_t stream) {
  const float* x         = (const float*)d_in[0];
  const float* node_pos  = (const float*)d_in[1];
  const float* log_sigma = (const float*)d_in[2];
  const float* WQ_w      = (const float*)d_in[3];
  const float* WQ_b      = (const float*)d_in[4];
  const float* WK_w      = (const float*)d_in[5];
  const float* WK_b      = (const float*)d_in[6];
  const float* gcn_w     = (const float*)d_in[7];
  const float* gcn_b     = (const float*)d_in[8];
  const float* Wa_w      = (const float*)d_in[9];
  const float* Wa_b      = (const float*)d_in[10];
  const float* wa_w      = (const float*)d_in[11];
  const float* wa_b      = (const float*)d_in[12];
  const float* ln_g      = (const float*)d_in[13];
  const float* ln_b      = (const float*)d_in[14];

  float* h = (float*)d_out;
  // workspace layout (bytes), total ~40.9 MB
  char* w = (char*)d_ws;
  float*  Msp   = (float*)w;  w += (size_t)KS * NN * NN * 4;        // 3.1 MB
  ushort* Qb    = (ushort*)w; w += (size_t)BT * NN * QSTRIDE * 2;   // 6.3 MB
  ushort* KT    = (ushort*)w; w += (size_t)BT * KS * DKE * NN * 2;  // 6.3 MB
  ushort* hb16  = (ushort*)w; w += (size_t)BT * NN * DM * 2;        // 8.4 MB
  float*  hagg  = (float*)w;  w += (size_t)BT * NN * DM * 4;        // 16.8 MB
  float*  alpha = (float*)w;  w += (size_t)BT * KS * 4;

  k_init<<<4096, 256, 0, stream>>>(x, h, hb16);
  k_msp<<<dim3(2, NN), 256, 0, stream>>>(node_pos, log_sigma, Msp);
  for (int l = 0; l < LL; ++l) {
    k_alpha<<<BT, 512, 0, stream>>>(h, Wa_w, Wa_b, wa_w, wa_b, l, alpha);
    k_qkproj<<<dim3(NN / 4, BT), 192, 0, stream>>>(h, WQ_w, WQ_b, WK_w, WK_b, Qb, KT);
    k_attn<<<dim3(NN / RB, BT), 512, 0, stream>>>(Qb, KT, hb16, Msp, alpha, hagg);
    k_gcnln<<<dim3(NN / 4, BT), 128, 0, stream>>>(h, hagg, gcn_w, gcn_b, ln_g, ln_b, l, hb16);
  }
}

// Round 6
// 1294.391 us; speedup vs baseline: 3.2693x; 1.0368x over previous
//
#include <hip/hip_runtime.h>
#include <hip/hip_bf16.h>
#include <cstdint>

// Problem constants: B=4,T=16 -> BT=64, N=512, D=128, K_SCALES=3, L_LAYERS=3,
// DK=32, POS_D=16, ALFA_H=32
#define BT 64
#define NN 512
#define DM 128
#define DKE 32
#define KS 3
#define LL 3
#define AHD 32
#define PD 16
#define QS 96        // per-row Q/K: 3 scales * 32 (bf16)
#define NPAD 104     // LDS row pad for Q/K tiles (208B = 13*16 -> 2-way banks)
#define RB 64        // n-rows per attn block
#define JTILE 64     // j-tile
#define INV_SQRT_DK 0.17677669529663687f
#define LN_EPS_F 1e-5f

typedef __attribute__((ext_vector_type(8))) short short8;
typedef __attribute__((ext_vector_type(4))) float floatx4;

__device__ __forceinline__ float wave_rsum(float v) {
#pragma unroll
  for (int o = 32; o > 0; o >>= 1) v += __shfl_xor(v, o, 64);
  return v;
}
__device__ __forceinline__ ushort f2bf(float f) {
  uint32_t u = __float_as_uint(f);
  u += 0x7fffu + ((u >> 16) & 1u);  // RTNE
  return (ushort)(u >> 16);
}
__device__ __forceinline__ float bf2f(ushort v) { return __uint_as_float((uint)v << 16); }

// --- K0: spatial masks Mb[k][i][j] = bf16(exp(-D2(i,j)/(2*sigma_k^2))) ----
__global__ void k_msp(const float* __restrict__ pos, const float* __restrict__ log_sigma,
                      ushort* __restrict__ Mb) {
  int j = blockIdx.x * 256 + threadIdx.x;
  int i = blockIdx.y;
  const float* pi = pos + i * PD;
  const float* pj = pos + j * PD;
  float d2 = 0.f;
#pragma unroll
  for (int p = 0; p < PD; ++p) {
    float df = pi[p] - pj[p];
    d2 += df * df;
  }
#pragma unroll
  for (int k = 0; k < KS; ++k) {
    float sg = fmaxf(__expf(log_sigma[k]), 1e-3f);
    float c = -0.5f / (sg * sg);
    Mb[(size_t)k * NN * NN + (size_t)i * NN + j] = f2bf(__expf(c * d2));
  }
}

// --- K1: per-bt scale-mix weights alpha[bt][3] ----------------------------
__global__ void k_alpha(const float* __restrict__ h, const float* __restrict__ Wa_w,
                        const float* __restrict__ Wa_b, const float* __restrict__ wa_w,
                        const float* __restrict__ wa_b, int l, float* __restrict__ alpha) {
  int bt = blockIdx.x;
  int tid = threadIdx.x;  // 512 threads
  int d = tid & (DM - 1);
  int sl = tid >> 7;
  __shared__ float part[4][DM];
  __shared__ float hm[DM];
  __shared__ float ah[AHD];
  const float* hb = h + (size_t)bt * NN * DM;
  float s = 0.f;
  for (int nn = 0; nn < NN / 4; ++nn) s += hb[(size_t)(sl * (NN / 4) + nn) * DM + d];
  part[sl][d] = s;
  __syncthreads();
  if (sl == 0) hm[d] = (part[0][d] + part[1][d] + part[2][d] + part[3][d]) * (1.f / NN);
  __syncthreads();
  if (tid < AHD) {
    const float* w = Wa_w + ((size_t)l * AHD + tid) * DM;
    float a = Wa_b[l * AHD + tid];
    for (int dd = 0; dd < DM; ++dd) a += hm[dd] * w[dd];
    ah[tid] = fmaxf(a, 0.f);
  }
  __syncthreads();
  if (tid == 0) {
    float lg[KS];
    float m = -1e30f;
    for (int k = 0; k < KS; ++k) {
      float v = wa_b[l * KS + k];
      const float* w = wa_w + ((size_t)l * KS + k) * AHD;
      for (int hh = 0; hh < AHD; ++hh) v += ah[hh] * w[hh];
      lg[k] = v;
      m = fmaxf(m, v);
    }
    float se = 0.f;
    for (int k = 0; k < KS; ++k) {
      lg[k] = __expf(lg[k] - m);
      se += lg[k];
    }
    float inv = 1.f / se;
    for (int k = 0; k < KS; ++k) alpha[bt * KS + k] = lg[k] * inv;
  }
}

// --- K2: Q/K projections; both row-major bf16 [bt][n][k*32+e].
//     Q is pre-scaled by 1/sqrt(dk). -------------------------------------
__global__ void k_qkproj(const float* __restrict__ h, const float* __restrict__ WQ_w,
                         const float* __restrict__ WQ_b, const float* __restrict__ WK_w,
                         const float* __restrict__ WK_b, ushort* __restrict__ Qb,
                         ushort* __restrict__ Kb) {
  int bt = blockIdx.y;
  int n0 = blockIdx.x * 4;
  int tid = threadIdx.x;  // 192 threads
  __shared__ float hl[4 * DM];
  const float* hbp = h + ((size_t)bt * NN + n0) * DM;
  for (int i = tid; i < 4 * DM; i += 192) hl[i] = hbp[i];
  __syncthreads();
  int k = tid >> 6;
  int rem = tid & 63;
  int qk = rem >> 5;
  int e = rem & 31;
  const float* W = (qk ? WK_w : WQ_w) + ((size_t)k * DKE + e) * DM;
  float bias = (qk ? WK_b : WQ_b)[k * DKE + e];
  float acc[4] = {bias, bias, bias, bias};
  const float4* W4 = (const float4*)W;
  const float4* h4 = (const float4*)hl;
#pragma unroll 8
  for (int d4 = 0; d4 < DM / 4; ++d4) {
    float4 w = W4[d4];
#pragma unroll
    for (int r = 0; r < 4; ++r) {
      float4 hv = h4[r * 32 + d4];
      acc[r] += w.x * hv.x + w.y * hv.y + w.z * hv.z + w.w * hv.w;
    }
  }
  ushort* out = (qk ? Kb : Qb) + ((size_t)bt * NN + n0) * QS + k * DKE + e;
  if (qk == 0) {
#pragma unroll
    for (int r = 0; r < 4; ++r) out[(size_t)r * QS] = f2bf(acc[r] * INV_SQRT_DK);
  } else {
#pragma unroll
    for (int r = 0; r < 4; ++r) out[(size_t)r * QS] = f2bf(acc[r]);
  }
}

// --- K_trans: hT[bt][d][n] = bf16(h[bt][n][d]) ----------------------------
__global__ void k_trans(const float* __restrict__ h, ushort* __restrict__ hT) {
  int bt = blockIdx.y, n0 = blockIdx.x * 64, t = threadIdx.x;  // 256 threads
  __shared__ ushort T[64][132];
  const float4* src = (const float4*)(h + ((size_t)bt * NN + n0) * DM);
#pragma unroll
  for (int i = 0; i < 8; ++i) {
    int idx = t + i * 256;  // 2048 float4
    float4 v = src[idx];
    int n = idx >> 5, d0 = (idx & 31) * 4;
    T[n][d0] = f2bf(v.x); T[n][d0 + 1] = f2bf(v.y);
    T[n][d0 + 2] = f2bf(v.z); T[n][d0 + 3] = f2bf(v.w);
  }
  __syncthreads();
#pragma unroll
  for (int i = 0; i < 8; ++i) {
    int idx = t + i * 256;  // 2048 uint2-chunks: d = idx>>4, nst = (idx&15)*4
    int d = idx >> 4, nst = (idx & 15) * 4;
    uint2 o;
    o.x = (uint)T[nst][d] | ((uint)T[nst + 1][d] << 16);
    o.y = (uint)T[nst + 2][d] | ((uint)T[nst + 3][d] << 16);
    *(uint2*)&hT[((size_t)bt * DM + d) * NN + n0 + nst] = o;
  }
}

// --- K3: fused 3-scale masked attention via MFMA --------------------------
// Block: 64 n-rows, 8 waves. Per j-tile(64): scores S^T = K*Q^T (MFMA),
// E_k = exp(S^T * mask) -> swizzled LDS; PV: O_k^T += hT * E_k^T (MFMA).
// Epilogue: O = sum_k (alpha_k / l_k) O_k; l_k = rowsum(E_k).
__global__ void __launch_bounds__(512, 1) k_attn(
    const ushort* __restrict__ Qb, const ushort* __restrict__ Kb,
    const ushort* __restrict__ hT, const ushort* __restrict__ Mb,
    const float* __restrict__ alpha, float* __restrict__ hagg) {
  int bt = blockIdx.y;
  int n0 = blockIdx.x * RB;
  int tid = threadIdx.x;
  int wv = tid >> 6, lane = tid & 63;
  int l15 = lane & 15, lg = lane >> 4;

  __shared__ __align__(16) ushort Qs[RB * NPAD];     // 13312 B
  __shared__ __align__(16) ushort Ksl[JTILE * NPAD]; // 13312 B
  __shared__ __align__(16) ushort Ws[KS * RB * JTILE]; // 24576 B (swizzled)
  __shared__ float lred[8][KS][2][16];               // 3072 B

  // stage Q tile (64 rows x 96 ushorts -> pad 104)
  {
    const uint2* qsrc = (const uint2*)(Qb + ((size_t)bt * NN + n0) * QS);
    for (int c = tid; c < 768; c += 512) {
      int row = c / 12, col = c % 12;
      *(uint2*)&Qs[row * NPAD + col * 8] = qsrc[c];
    }
  }
  float al[KS];
#pragma unroll
  for (int k = 0; k < KS; ++k) al[k] = alpha[bt * KS + k];

  floatx4 accO[KS][4];
#pragma unroll
  for (int k = 0; k < KS; ++k)
#pragma unroll
    for (int nt = 0; nt < 4; ++nt) accO[k][nt] = (floatx4){0.f, 0.f, 0.f, 0.f};
  float ls[KS][2];
#pragma unroll
  for (int k = 0; k < KS; ++k) { ls[k][0] = 0.f; ls[k][1] = 0.f; }

  int j16 = wv & 3, nh = wv >> 2;
  int swz = (l15 & 7) << 3;  // Ws ushort-index XOR swizzle

  for (int t = 0; t < NN / JTILE; ++t) {
    __syncthreads();  // B1: prev PV / Ks reads done
    // prefetch PV A-frags (global hT) for this tile - consumed after B3
    short8 a0 = *(const short8*)&hT[((size_t)bt * DM + wv * 16 + l15) * NN + t * JTILE + lg * 8];
    short8 a1 = *(const short8*)&hT[((size_t)bt * DM + wv * 16 + l15) * NN + t * JTILE + 32 + lg * 8];
    // stage K tile
    {
      const uint2* ksrc = (const uint2*)(Kb + ((size_t)bt * NN + t * JTILE) * QS);
      for (int c = tid; c < 768; c += 512) {
        int row = c / 12, col = c % 12;
        *(uint2*)&Ksl[row * NPAD + col * 8] = ksrc[c];
      }
    }
    __syncthreads();  // B2
    // scores + exp -> Ws
#pragma unroll
    for (int k = 0; k < KS; ++k) {
      short8 ka = *(const short8*)&Ksl[(j16 * 16 + l15) * NPAD + k * 32 + lg * 8];
#pragma unroll
      for (int nt2 = 0; nt2 < 2; ++nt2) {
        int n16 = (nh * 2 + nt2) * 16;
        short8 qf = *(const short8*)&Qs[(n16 + l15) * NPAD + k * 32 + lg * 8];
        floatx4 c = __builtin_amdgcn_mfma_f32_16x16x32_bf16(
            ka, qf, (floatx4){0.f, 0.f, 0.f, 0.f}, 0, 0, 0);
        const ushort* mp = Mb + ((size_t)k * NN + n0 + n16 + l15) * NN +
                           t * JTILE + j16 * 16 + lg * 4;
        ushort4 mv = *(const ushort4*)mp;
        float v0 = __expf(c[0] * bf2f(mv.x));
        float v1 = __expf(c[1] * bf2f(mv.y));
        float v2 = __expf(c[2] * bf2f(mv.z));
        float v3 = __expf(c[3] * bf2f(mv.w));
        ls[k][nt2] += v0 + v1 + v2 + v3;
        uint2 pk2;
        pk2.x = (uint)f2bf(v0) | ((uint)f2bf(v1) << 16);
        pk2.y = (uint)f2bf(v2) | ((uint)f2bf(v3) << 16);
        int row = k * RB + n16 + l15;
        int jloc = j16 * 16 + lg * 4;
        *(uint2*)&Ws[row * JTILE + (jloc ^ swz)] = pk2;
      }
    }
    __syncthreads();  // B3: Ws visible
    // PV: wave = d-tile wv
#pragma unroll
    for (int k = 0; k < KS; ++k) {
#pragma unroll
      for (int nt = 0; nt < 4; ++nt) {
        int row = k * RB + nt * 16 + l15;
        short8 e0 = *(const short8*)&Ws[row * JTILE + ((lg * 8) ^ swz)];
        accO[k][nt] = __builtin_amdgcn_mfma_f32_16x16x32_bf16(a0, e0, accO[k][nt], 0, 0, 0);
        short8 e1 = *(const short8*)&Ws[row * JTILE + ((32 + lg * 8) ^ swz)];
        accO[k][nt] = __builtin_amdgcn_mfma_f32_16x16x32_bf16(a1, e1, accO[k][nt], 0, 0, 0);
      }
    }
  }

  // row-sum reduction -> linv
#pragma unroll
  for (int k = 0; k < KS; ++k)
#pragma unroll
    for (int nt2 = 0; nt2 < 2; ++nt2) {
      float v = ls[k][nt2];
      v += __shfl_xor(v, 16, 64);
      v += __shfl_xor(v, 32, 64);
      if (lane < 16) lred[wv][k][nt2][lane] = v;
    }
  __syncthreads();
  float linv[KS][4];
#pragma unroll
  for (int k = 0; k < KS; ++k)
#pragma unroll
    for (int nt = 0; nt < 4; ++nt) {
      int h2 = nt >> 1, t2 = nt & 1;
      float s = lred[h2 * 4 + 0][k][t2][l15] + lred[h2 * 4 + 1][k][t2][l15] +
                lred[h2 * 4 + 2][k][t2][l15] + lred[h2 * 4 + 3][k][t2][l15];
      linv[k][nt] = al[k] / s;
    }
  // epilogue: combine scales, write hagg[bt][n][d]
#pragma unroll
  for (int nt = 0; nt < 4; ++nt) {
    float4 o;
    o.x = linv[0][nt] * accO[0][nt][0] + linv[1][nt] * accO[1][nt][0] + linv[2][nt] * accO[2][nt][0];
    o.y = linv[0][nt] * accO[0][nt][1] + linv[1][nt] * accO[1][nt][1] + linv[2][nt] * accO[2][nt][1];
    o.z = linv[0][nt] * accO[0][nt][2] + linv[1][nt] * accO[1][nt][2] + linv[2][nt] * accO[2][nt][2];
    o.w = linv[0][nt] * accO[0][nt][3] + linv[1][nt] * accO[1][nt][3] + linv[2][nt] * accO[2][nt][3];
    *(float4*)&hagg[((size_t)bt * NN + n0 + nt * 16 + l15) * DM + wv * 16 + lg * 4] = o;
  }
}

// --- K4: h = LayerNorm(h + relu(h_agg @ gcn_w^T + gcn_b)) (in place) ------
__global__ void k_gcnln(float* __restrict__ h, const float* __restrict__ hagg,
                        const float* __restrict__ gcn_w, const float* __restrict__ gcn_b,
                        const float* __restrict__ ln_g, const float* __restrict__ ln_b,
                        int l) {
  int bt = blockIdx.y, n0 = blockIdx.x * 4, tid = threadIdx.x;  // 128 threads
  __shared__ float gl[4 * DM];
  __shared__ float red[2][4][2];
  const float* gb = hagg + ((size_t)bt * NN + n0) * DM;
  for (int i = tid; i < 4 * DM; i += 128) gl[i] = gb[i];
  __syncthreads();
  int d = tid;
  const float* W = gcn_w + ((size_t)l * DM + d) * DM;
  float b0 = gcn_b[l * DM + d];
  float acc[4] = {b0, b0, b0, b0};
  const float4* W4 = (const float4*)W;
  const float4* g4 = (const float4*)gl;
#pragma unroll 8
  for (int d4 = 0; d4 < DM / 4; ++d4) {
    float4 w = W4[d4];
#pragma unroll
    for (int r = 0; r < 4; ++r) {
      float4 hv = g4[r * 32 + d4];
      acc[r] += w.x * hv.x + w.y * hv.y + w.z * hv.z + w.w * hv.w;
    }
  }
  float* hbp = h + ((size_t)bt * NN + n0) * DM;
  float y[4];
#pragma unroll
  for (int r = 0; r < 4; ++r) y[r] = hbp[(size_t)r * DM + d] + fmaxf(acc[r], 0.f);
  int wv = tid >> 6, lane = tid & 63;
#pragma unroll
  for (int r = 0; r < 4; ++r) {
    float s1 = wave_rsum(y[r]);
    float s2 = wave_rsum(y[r] * y[r]);
    if (lane == 0) { red[wv][r][0] = s1; red[wv][r][1] = s2; }
  }
  __syncthreads();
  float g = ln_g[l * DM + d], bb = ln_b[l * DM + d];
#pragma unroll
  for (int r = 0; r < 4; ++r) {
    float mu = (red[0][r][0] + red[1][r][0]) * (1.f / DM);
    float ms = (red[0][r][1] + red[1][r][1]) * (1.f / DM);
    float var = ms - mu * mu;
    float inv = rsqrtf(var + LN_EPS_F);
    hbp[(size_t)r * DM + d] = (y[r] - mu) * inv * g + bb;
  }
}

extern "C" void kernel_launch(void* const* d_in, const int* in_sizes, int n_in,
                              void* d_out, int out_size, void* d_ws, size_t ws_size,
                              hipStream_t stream) {
  const float* x         = (const float*)d_in[0];
  const float* node_pos  = (const float*)d_in[1];
  const float* log_sigma = (const float*)d_in[2];
  const float* WQ_w      = (const float*)d_in[3];
  const float* WQ_b      = (const float*)d_in[4];
  const float* WK_w      = (const float*)d_in[5];
  const float* WK_b      = (const float*)d_in[6];
  const float* gcn_w     = (const float*)d_in[7];
  const float* gcn_b     = (const float*)d_in[8];
  const float* Wa_w      = (const float*)d_in[9];
  const float* Wa_b      = (const float*)d_in[10];
  const float* wa_w      = (const float*)d_in[11];
  const float* wa_b      = (const float*)d_in[12];
  const float* ln_g      = (const float*)d_in[13];
  const float* ln_b      = (const float*)d_in[14];

  float* h = (float*)d_out;
  char* w = (char*)d_ws;
  ushort* Mb    = (ushort*)w; w += (size_t)KS * NN * NN * 2;   // 1.6 MB
  ushort* Qb    = (ushort*)w; w += (size_t)BT * NN * QS * 2;   // 6.3 MB
  ushort* Kb    = (ushort*)w; w += (size_t)BT * NN * QS * 2;   // 6.3 MB
  ushort* hT    = (ushort*)w; w += (size_t)BT * DM * NN * 2;   // 8.4 MB
  float*  hagg  = (float*)w;  w += (size_t)BT * NN * DM * 4;   // 16.8 MB
  float*  alpha = (float*)w;  w += (size_t)BT * KS * 4;

  hipMemcpyAsync(h, x, (size_t)BT * NN * DM * sizeof(float),
                 hipMemcpyDeviceToDevice, stream);
  k_msp<<<dim3(2, NN), 256, 0, stream>>>(node_pos, log_sigma, Mb);
  for (int l = 0; l < LL; ++l) {
    k_alpha<<<BT, 512, 0, stream>>>(h, Wa_w, Wa_b, wa_w, wa_b, l, alpha);
    k_qkproj<<<dim3(NN / 4, BT), 192, 0, stream>>>(h, WQ_w, WQ_b, WK_w, WK_b, Qb, Kb);
    k_trans<<<dim3(NN / 64, BT), 256, 0, stream>>>(h, hT);
    k_attn<<<dim3(NN / RB, BT), 512, 0, stream>>>(Qb, Kb, hT, Mb, alpha, hagg);
    k_gcnln<<<dim3(NN / 4, BT), 128, 0, stream>>>(h, hagg, gcn_w, gcn_b, ln_g, ln_b, l);
  }
}

// Round 13
// 560.635 us; speedup vs baseline: 7.5481x; 2.3088x over previous
//
#include <hip/hip_runtime.h>
#include <hip/hip_bf16.h>
#include <cstdint>

// Problem constants: B=4,T=16 -> BT=64, N=512, D=128, K_SCALES=3, L_LAYERS=3,
// DK=32, POS_D=16, ALFA_H=32
#define BT 64
#define NN 512
#define DM 128
#define DKE 32
#define KS 3
#define LL 3
#define AHD 32
#define PD 16
#define EP 192       // interleaved QK row: Q[0..95] (pre-scaled), K[96..191]
#define NPAD 104     // attn LDS row pad (208B = 13*16B)
#define HP 136       // qkproj h-tile row pad (272B)
#define OP 200       // qkproj out-tile row pad (400B)
#define RB 64        // n-rows per attn block
#define JTILE 64     // attn j-tile
#define INV_SQRT_DK 0.17677669529663687f
#define LN_EPS_F 1e-5f

typedef __attribute__((ext_vector_type(8))) short short8;
typedef __attribute__((ext_vector_type(4))) float floatx4;

__device__ __forceinline__ float wave_rsum(float v) {
#pragma unroll
  for (int o = 32; o > 0; o >>= 1) v += __shfl_xor(v, o, 64);
  return v;
}
__device__ __forceinline__ ushort f2bf(float f) {
  uint32_t u = __float_as_uint(f);
  u += 0x7fffu + ((u >> 16) & 1u);  // RTNE
  return (ushort)(u >> 16);
}
__device__ __forceinline__ float bf2f(ushort v) { return __uint_as_float((uint)v << 16); }

// --- K_wprep (once): Wb[e'][d] bf16 (Q rows pre-scaled), biasf[192] -------
__global__ void k_wprep(const float* __restrict__ WQ_w, const float* __restrict__ WQ_b,
                        const float* __restrict__ WK_w, const float* __restrict__ WK_b,
                        ushort* __restrict__ Wb, float* __restrict__ biasf) {
  int idx = blockIdx.x * 256 + threadIdx.x;  // 24576
  int ep = idx >> 7, d = idx & 127;
  bool isk = ep >= 96;
  int ke = isk ? ep - 96 : ep;
  float w = (isk ? WK_w : WQ_w)[(size_t)ke * DM + d];
  Wb[idx] = f2bf(isk ? w : w * INV_SQRT_DK);
  if (d == 0) {
    float b = (isk ? WK_b : WQ_b)[ke];
    biasf[ep] = isk ? b : b * INV_SQRT_DK;
  }
}

// --- K0: spatial masks Mb[k][i][j] = bf16(exp(-D2(i,j)/(2*sigma_k^2))) ----
__global__ void k_msp(const float* __restrict__ pos, const float* __restrict__ log_sigma,
                      ushort* __restrict__ Mb) {
  int j = blockIdx.x * 256 + threadIdx.x;
  int i = blockIdx.y;
  const float* pi = pos + i * PD;
  const float* pj = pos + j * PD;
  float d2 = 0.f;
#pragma unroll
  for (int p = 0; p < PD; ++p) {
    float df = pi[p] - pj[p];
    d2 += df * df;
  }
#pragma unroll
  for (int k = 0; k < KS; ++k) {
    float sg = fmaxf(__expf(log_sigma[k]), 1e-3f);
    float c = -0.5f / (sg * sg);
    Mb[(size_t)k * NN * NN + (size_t)i * NN + j] = f2bf(__expf(c * d2));
  }
}

// --- K2 v2: QK projections as MFMA GEMM + hT emission + alpha partials ----
__global__ void __launch_bounds__(512, 2) k_qkproj(
    const float* __restrict__ h, const ushort* __restrict__ Wb,
    const float* __restrict__ biasf, ushort* __restrict__ QK,
    ushort* __restrict__ hT, float* __restrict__ part) {
  int bt = blockIdx.y, n0 = blockIdx.x * 64, tid = threadIdx.x;
  int wv = tid >> 6, lane = tid & 63, l15 = lane & 15, lg = lane >> 4;
  __shared__ __align__(16) ushort hs[64 * HP];   // 17.4 KB
  __shared__ __align__(16) ushort ot[64 * OP];   // 25.6 KB
  __shared__ float4 pt[16][32];                  // 8 KB

  // stage h (f32 -> bf16 LDS) + f32 alpha partial sums
  const float4* hsrc = (const float4*)(h + ((size_t)bt * NN + n0) * DM);
  float4 psum = {0.f, 0.f, 0.f, 0.f};
#pragma unroll
  for (int j = 0; j < 4; ++j) {
    int c = tid + j * 512;  // n = c>>5, d0 = (c&31)*4
    float4 v = hsrc[c];
    psum.x += v.x; psum.y += v.y; psum.z += v.z; psum.w += v.w;
    ushort4 u;
    u.x = f2bf(v.x); u.y = f2bf(v.y); u.z = f2bf(v.z); u.w = f2bf(v.w);
    *(ushort4*)&hs[(c >> 5) * HP + (c & 31) * 4] = u;
  }
  pt[tid >> 5][tid & 31] = psum;
  __syncthreads();
  if (tid < DM) {
    int dq = tid >> 2, cm = tid & 3;
    float s = 0.f;
#pragma unroll
    for (int i = 0; i < 16; ++i) {
      float4 p = pt[i][dq];
      s += (cm == 0 ? p.x : cm == 1 ? p.y : cm == 2 ? p.z : p.w);
    }
    part[((size_t)bt * 8 + blockIdx.x) * DM + tid] = s;
  }

  int rg = wv >> 2, cg = wv & 3;
  floatx4 acc[2][3];
#pragma unroll
  for (int rt = 0; rt < 2; ++rt)
#pragma unroll
    for (int ct = 0; ct < 3; ++ct) acc[rt][ct] = (floatx4){0.f, 0.f, 0.f, 0.f};
#pragma unroll
  for (int ks = 0; ks < 4; ++ks) {
    short8 hf0 = *(const short8*)&hs[(rg * 32 + l15) * HP + ks * 32 + lg * 8];
    short8 hf1 = *(const short8*)&hs[(rg * 32 + 16 + l15) * HP + ks * 32 + lg * 8];
#pragma unroll
    for (int ct = 0; ct < 3; ++ct) {
      short8 wf = *(const short8*)&Wb[(size_t)(cg * 48 + ct * 16 + l15) * DM + ks * 32 + lg * 8];
      acc[0][ct] = __builtin_amdgcn_mfma_f32_16x16x32_bf16(wf, hf0, acc[0][ct], 0, 0, 0);
      acc[1][ct] = __builtin_amdgcn_mfma_f32_16x16x32_bf16(wf, hf1, acc[1][ct], 0, 0, 0);
    }
  }
  // epilogue: +bias, bf16, to padded LDS tile (lane owns 4 consecutive e')
#pragma unroll
  for (int rt = 0; rt < 2; ++rt)
#pragma unroll
    for (int ct = 0; ct < 3; ++ct) {
      int e0 = cg * 48 + ct * 16 + lg * 4;
      float4 bv = *(const float4*)&biasf[e0];
      int n = rg * 32 + rt * 16 + l15;
      ushort4 u;
      u.x = f2bf(acc[rt][ct][0] + bv.x);
      u.y = f2bf(acc[rt][ct][1] + bv.y);
      u.z = f2bf(acc[rt][ct][2] + bv.z);
      u.w = f2bf(acc[rt][ct][3] + bv.w);
      *(ushort4*)&ot[n * OP + e0] = u;
    }
  // hT[bt][d][n0..+63] from hs (hs stable after first barrier)
#pragma unroll
  for (int j = 0; j < 4; ++j) {
    int idx = tid + j * 512;
    int d = idx >> 4, n4 = (idx & 15) * 4;
    uint2 o;  // 8 bytes = 4 packed bf16 (intentionally uint2)
    o.x = (uint)hs[n4 * HP + d] | ((uint)hs[(n4 + 1) * HP + d] << 16);
    o.y = (uint)hs[(n4 + 2) * HP + d] | ((uint)hs[(n4 + 3) * HP + d] << 16);
    *(uint2*)&hT[((size_t)bt * DM + d) * NN + n0 + n4] = o;
  }
  __syncthreads();
  // coalesced copy ot -> QK (contiguous 24 KB per block)
  const uint4* src = (const uint4*)ot;
  uint4* dst = (uint4*)(QK + ((size_t)bt * NN + n0) * EP);
#pragma unroll
  for (int p = 0; p < 3; ++p) {
    int idx = tid + p * 512;       // 1536 chunks of 16 B
    int row = idx / 24, q = idx - row * 24;
    dst[idx] = src[row * 25 + q];  // OP = 25 uint4, EP = 24 uint4
  }
}

// --- K1 v2: finish alpha from partials (no big h read) --------------------
__global__ void k_alpha_fin(const float* __restrict__ part, const float* __restrict__ Wa_w,
                            const float* __restrict__ Wa_b, const float* __restrict__ wa_w,
                            const float* __restrict__ wa_b, int l, float* __restrict__ alpha) {
  int bt = blockIdx.x, tid = threadIdx.x;  // 128 threads
  __shared__ float hm[DM];
  __shared__ float ah[AHD];
  {
    float s = 0.f;
#pragma unroll
    for (int i = 0; i < 8; ++i) s += part[((size_t)bt * 8 + i) * DM + tid];
    hm[tid] = s * (1.f / NN);
  }
  __syncthreads();
  if (tid < AHD) {
    const float* w = Wa_w + ((size_t)l * AHD + tid) * DM;
    float a = Wa_b[l * AHD + tid];
    for (int d = 0; d < DM; ++d) a += hm[d] * w[d];
    ah[tid] = fmaxf(a, 0.f);
  }
  __syncthreads();
  if (tid == 0) {
    float lg[KS];
    float m = -1e30f;
    for (int k = 0; k < KS; ++k) {
      float v = wa_b[l * KS + k];
      const float* w = wa_w + ((size_t)l * KS + k) * AHD;
      for (int hh = 0; hh < AHD; ++hh) v += ah[hh] * w[hh];
      lg[k] = v;
      m = fmaxf(m, v);
    }
    float se = 0.f;
    for (int k = 0; k < KS; ++k) {
      lg[k] = __expf(lg[k] - m);
      se += lg[k];
    }
    float inv = 1.f / se;
    for (int k = 0; k < KS; ++k) alpha[bt * KS + k] = lg[k] * inv;
  }
}

// --- K3: fused 3-scale masked attention via MFMA (QK interleaved) ---------
// BUGFIX (r7->r8): staging chunks are uint4 (16 B). uint2 (8 B) halved the
// effective row stride -> scrambled Q/K tiles; masked in r5/6 by near-uniform
// softmax (Gaussian masks crush scores), exposed at absmax 0.30 in r7.
__global__ void __launch_bounds__(512, 1) k_attn(
    const ushort* __restrict__ QK, const ushort* __restrict__ hT,
    const ushort* __restrict__ Mb, const float* __restrict__ alpha,
    float* __restrict__ hagg) {
  int bt = blockIdx.y;
  int n0 = blockIdx.x * RB;
  int tid = threadIdx.x;
  int wv = tid >> 6, lane = tid & 63;
  int l15 = lane & 15, lg = lane >> 4;

  __shared__ __align__(16) ushort Qs[RB * NPAD];       // 13312 B
  __shared__ __align__(16) ushort Ksl[JTILE * NPAD];   // 13312 B
  __shared__ __align__(16) ushort Ws[KS * RB * JTILE]; // 24576 B (swizzled)
  __shared__ float lred[8][KS][2][16];                 // 3072 B

  // stage Q tile: rows n0..+63, ushort cols 0..95 of QK (row = 24 uint4)
  {
    const uint4* qsrc = (const uint4*)(QK + ((size_t)bt * NN + n0) * EP);
    for (int c = tid; c < 768; c += 512) {
      int row = c / 12, col = c % 12;
      *(uint4*)&Qs[row * NPAD + col * 8] = qsrc[row * 24 + col];
    }
  }
  float al[KS];
#pragma unroll
  for (int k = 0; k < KS; ++k) al[k] = alpha[bt * KS + k];

  floatx4 accO[KS][4];
#pragma unroll
  for (int k = 0; k < KS; ++k)
#pragma unroll
    for (int nt = 0; nt < 4; ++nt) accO[k][nt] = (floatx4){0.f, 0.f, 0.f, 0.f};
  float ls[KS][2];
#pragma unroll
  for (int k = 0; k < KS; ++k) { ls[k][0] = 0.f; ls[k][1] = 0.f; }

  int j16 = wv & 3, nh = wv >> 2;
  int swz = (l15 & 7) << 3;
  const uint4* ksrc = (const uint4*)(QK + (size_t)bt * NN * EP);

  for (int t = 0; t < NN / JTILE; ++t) {
    __syncthreads();  // B1
    short8 a0 = *(const short8*)&hT[((size_t)bt * DM + wv * 16 + l15) * NN + t * JTILE + lg * 8];
    short8 a1 = *(const short8*)&hT[((size_t)bt * DM + wv * 16 + l15) * NN + t * JTILE + 32 + lg * 8];
    // stage K tile: rows t*64..+63, ushort cols 96..191 (= uint4 12..23)
    for (int c = tid; c < 768; c += 512) {
      int row = c / 12, col = c % 12;
      *(uint4*)&Ksl[row * NPAD + col * 8] = ksrc[(t * JTILE + row) * 24 + 12 + col];
    }
    __syncthreads();  // B2
#pragma unroll
    for (int k = 0; k < KS; ++k) {
      short8 ka = *(const short8*)&Ksl[(j16 * 16 + l15) * NPAD + k * 32 + lg * 8];
#pragma unroll
      for (int nt2 = 0; nt2 < 2; ++nt2) {
        int n16 = (nh * 2 + nt2) * 16;
        short8 qf = *(const short8*)&Qs[(n16 + l15) * NPAD + k * 32 + lg * 8];
        floatx4 c = __builtin_amdgcn_mfma_f32_16x16x32_bf16(
            ka, qf, (floatx4){0.f, 0.f, 0.f, 0.f}, 0, 0, 0);
        const ushort* mp = Mb + ((size_t)k * NN + n0 + n16 + l15) * NN +
                           t * JTILE + j16 * 16 + lg * 4;
        ushort4 mv = *(const ushort4*)mp;
        float v0 = __expf(c[0] * bf2f(mv.x));
        float v1 = __expf(c[1] * bf2f(mv.y));
        float v2 = __expf(c[2] * bf2f(mv.z));
        float v3 = __expf(c[3] * bf2f(mv.w));
        ls[k][nt2] += v0 + v1 + v2 + v3;
        uint2 pk2;
        pk2.x = (uint)f2bf(v0) | ((uint)f2bf(v1) << 16);
        pk2.y = (uint)f2bf(v2) | ((uint)f2bf(v3) << 16);
        int row = k * RB + n16 + l15;
        int jloc = j16 * 16 + lg * 4;
        *(uint2*)&Ws[row * JTILE + (jloc ^ swz)] = pk2;
      }
    }
    __syncthreads();  // B3
#pragma unroll
    for (int k = 0; k < KS; ++k) {
#pragma unroll
      for (int nt = 0; nt < 4; ++nt) {
        int row = k * RB + nt * 16 + l15;
        short8 e0 = *(const short8*)&Ws[row * JTILE + ((lg * 8) ^ swz)];
        accO[k][nt] = __builtin_amdgcn_mfma_f32_16x16x32_bf16(a0, e0, accO[k][nt], 0, 0, 0);
        short8 e1 = *(const short8*)&Ws[row * JTILE + ((32 + lg * 8) ^ swz)];
        accO[k][nt] = __builtin_amdgcn_mfma_f32_16x16x32_bf16(a1, e1, accO[k][nt], 0, 0, 0);
      }
    }
  }

#pragma unroll
  for (int k = 0; k < KS; ++k)
#pragma unroll
    for (int nt2 = 0; nt2 < 2; ++nt2) {
      float v = ls[k][nt2];
      v += __shfl_xor(v, 16, 64);
      v += __shfl_xor(v, 32, 64);
      if (lane < 16) lred[wv][k][nt2][lane] = v;
    }
  __syncthreads();
  float linv[KS][4];
#pragma unroll
  for (int k = 0; k < KS; ++k)
#pragma unroll
    for (int nt = 0; nt < 4; ++nt) {
      int h2 = nt >> 1, t2 = nt & 1;
      float s = lred[h2 * 4 + 0][k][t2][l15] + lred[h2 * 4 + 1][k][t2][l15] +
                lred[h2 * 4 + 2][k][t2][l15] + lred[h2 * 4 + 3][k][t2][l15];
      linv[k][nt] = al[k] / s;
    }
#pragma unroll
  for (int nt = 0; nt < 4; ++nt) {
    float4 o;
    o.x = linv[0][nt] * accO[0][nt][0] + linv[1][nt] * accO[1][nt][0] + linv[2][nt] * accO[2][nt][0];
    o.y = linv[0][nt] * accO[0][nt][1] + linv[1][nt] * accO[1][nt][1] + linv[2][nt] * accO[2][nt][1];
    o.z = linv[0][nt] * accO[0][nt][2] + linv[1][nt] * accO[1][nt][2] + linv[2][nt] * accO[2][nt][2];
    o.w = linv[0][nt] * accO[0][nt][3] + linv[1][nt] * accO[1][nt][3] + linv[2][nt] * accO[2][nt][3];
    *(float4*)&hagg[((size_t)bt * NN + n0 + nt * 16 + l15) * DM + wv * 16 + lg * 4] = o;
  }
}

// --- K4: h = LayerNorm(h + relu(h_agg @ gcn_w^T + gcn_b)) (in place) ------
__global__ void k_gcnln(float* __restrict__ h, const float* __restrict__ hagg,
                        const float* __restrict__ gcn_w, const float* __restrict__ gcn_b,
                        const float* __restrict__ ln_g, const float* __restrict__ ln_b,
                        int l) {
  int bt = blockIdx.y, n0 = blockIdx.x * 4, tid = threadIdx.x;  // 128 threads
  __shared__ float gl[4 * DM];
  __shared__ float red[2][4][2];
  const float* gb = hagg + ((size_t)bt * NN + n0) * DM;
  for (int i = tid; i < 4 * DM; i += 128) gl[i] = gb[i];
  __syncthreads();
  int d = tid;
  const float* W = gcn_w + ((size_t)l * DM + d) * DM;
  float b0 = gcn_b[l * DM + d];
  float acc[4] = {b0, b0, b0, b0};
  const float4* W4 = (const float4*)W;
  const float4* g4 = (const float4*)gl;
#pragma unroll 8
  for (int d4 = 0; d4 < DM / 4; ++d4) {
    float4 w = W4[d4];
#pragma unroll
    for (int r = 0; r < 4; ++r) {
      float4 hv = g4[r * 32 + d4];
      acc[r] += w.x * hv.x + w.y * hv.y + w.z * hv.z + w.w * hv.w;
    }
  }
  float* hbp = h + ((size_t)bt * NN + n0) * DM;
  float y[4];
#pragma unroll
  for (int r = 0; r < 4; ++r) y[r] = hbp[(size_t)r * DM + d] + fmaxf(acc[r], 0.f);
  int wv = tid >> 6, lane = tid & 63;
#pragma unroll
  for (int r = 0; r < 4; ++r) {
    float s1 = wave_rsum(y[r]);
    float s2 = wave_rsum(y[r] * y[r]);
    if (lane == 0) { red[wv][r][0] = s1; red[wv][r][1] = s2; }
  }
  __syncthreads();
  float g = ln_g[l * DM + d], bb = ln_b[l * DM + d];
#pragma unroll
  for (int r = 0; r < 4; ++r) {
    float mu = (red[0][r][0] + red[1][r][0]) * (1.f / DM);
    float ms = (red[0][r][1] + red[1][r][1]) * (1.f / DM);
    float var = ms - mu * mu;
    float inv = rsqrtf(var + LN_EPS_F);
    hbp[(size_t)r * DM + d] = (y[r] - mu) * inv * g + bb;
  }
}

extern "C" void kernel_launch(void* const* d_in, const int* in_sizes, int n_in,
                              void* d_out, int out_size, void* d_ws, size_t ws_size,
                              hipStream_t stream) {
  const float* x         = (const float*)d_in[0];
  const float* node_pos  = (const float*)d_in[1];
  const float* log_sigma = (const float*)d_in[2];
  const float* WQ_w      = (const float*)d_in[3];
  const float* WQ_b      = (const float*)d_in[4];
  const float* WK_w      = (const float*)d_in[5];
  const float* WK_b      = (const float*)d_in[6];
  const float* gcn_w     = (const float*)d_in[7];
  const float* gcn_b     = (const float*)d_in[8];
  const float* Wa_w      = (const float*)d_in[9];
  const float* Wa_b      = (const float*)d_in[10];
  const float* wa_w      = (const float*)d_in[11];
  const float* wa_b      = (const float*)d_in[12];
  const float* ln_g      = (const float*)d_in[13];
  const float* ln_b      = (const float*)d_in[14];

  float* h = (float*)d_out;
  char* w = (char*)d_ws;
  ushort* Mb    = (ushort*)w; w += (size_t)KS * NN * NN * 2;   // 1.57 MB
  ushort* QK    = (ushort*)w; w += (size_t)BT * NN * EP * 2;   // 12.6 MB
  ushort* hT    = (ushort*)w; w += (size_t)BT * DM * NN * 2;   // 8.4 MB
  float*  hagg  = (float*)w;  w += (size_t)BT * NN * DM * 4;   // 16.8 MB
  float*  alpha = (float*)w;  w += (size_t)BT * KS * 4 + 256;  // 1 KB
  ushort* Wb    = (ushort*)w; w += (size_t)EP * DM * 2;        // 49 KB
  float*  biasf = (float*)w;  w += (size_t)EP * 4 + 256;       // 1 KB
  float*  part  = (float*)w;  w += (size_t)BT * 8 * DM * 4;    // 262 KB

  hipMemcpyAsync(h, x, (size_t)BT * NN * DM * sizeof(float),
                 hipMemcpyDeviceToDevice, stream);
  k_wprep<<<96, 256, 0, stream>>>(WQ_w, WQ_b, WK_w, WK_b, Wb, biasf);
  k_msp<<<dim3(2, NN), 256, 0, stream>>>(node_pos, log_sigma, Mb);
  for (int l = 0; l < LL; ++l) {
    k_qkproj<<<dim3(NN / 64, BT), 512, 0, stream>>>(h, Wb, biasf, QK, hT, part);
    k_alpha_fin<<<BT, 128, 0, stream>>>(part, Wa_w, Wa_b, wa_w, wa_b, l, alpha);
    k_attn<<<dim3(NN / RB, BT), 512, 0, stream>>>(QK, hT, Mb, alpha, hagg);
    k_gcnln<<<dim3(NN / 4, BT), 128, 0, stream>>>(h, hagg, gcn_w, gcn_b, ln_g, ln_b, l);
  }
}